// Round 1
// baseline (155.705 us; speedup 1.0000x reference)
//
#include <hip/hip_runtime.h>
#include <hip/hip_bf16.h>

#define WIN 7
#define SHIFT_SZ 3
#define HEADS 4
#define WSQ 49
#define CH 128
#define HW 56

typedef short s16x8 __attribute__((ext_vector_type(8)));
typedef float f32x4 __attribute__((ext_vector_type(4)));

// ---------------- prep kernels ----------------

__global__ void prep_weights(const float* __restrict__ qkv_kernel,
                             const float* __restrict__ proj_kernel,
                             __hip_bfloat16* __restrict__ ws) {
  int idx = blockIdx.x * 256 + threadIdx.x;
  if (idx < 49152) {                      // WqkvT [384][128]
    int n = idx >> 7, c = idx & 127;
    ws[idx] = __float2bfloat16(qkv_kernel[c * 384 + n]);
  }
  if (idx < 16384) {                      // WprojT [128][128]
    int n = idx >> 7, c = idx & 127;
    ws[49152 + idx] = __float2bfloat16(proj_kernel[c * 128 + n]);
  }
}

// tbl[win][h][s][t] = rel_pos_bias + shift_mask, padded: t>=49 -> -30000
__global__ void prep_tbl(const float* __restrict__ rel_pos_table,
                         __hip_bfloat16* __restrict__ tbl) {
  int idx = blockIdx.x * 256 + threadIdx.x;   // 2^20 total
  int t = idx & 63;
  int s = (idx >> 6) & 63;
  int h = (idx >> 12) & 3;
  int win = idx >> 14;
  float v;
  if (t >= WSQ) v = -30000.f;
  else if (s >= WSQ) v = 0.f;
  else {
    int i1 = s / 7, j1 = s % 7, i2 = t / 7, j2 = t % 7;
    int ridx = (i1 - i2 + 6) * 13 + (j1 - j2 + 6);
    float bias = rel_pos_table[ridx * HEADS + h];
    int wy = win >> 3, wx = win & 7;
    // region ids in shifted-image coords; only last window row/col is split
    int rh1 = (wy < 7) ? 0 : (i1 < 4 ? 1 : 2);
    int rh2 = (wy < 7) ? 0 : (i2 < 4 ? 1 : 2);
    int rw1 = (wx < 7) ? 0 : (j1 < 4 ? 1 : 2);
    int rw2 = (wx < 7) ? 0 : (j2 < 4 ? 1 : 2);
    float mask = (rh1 == rh2 && rw1 == rw2) ? 0.f : -100.f;
    v = bias + mask;
  }
  tbl[idx] = __float2bfloat16(v);
}

// ---------------- fused main kernel ----------------
// one block = one window (4096 blocks), 512 threads = 8 waves
// LDS: [0,17408)      a/o buffer  bf16 [64][136]   (x-window, later O concat)
//      [17408,58368)  q [4][64][40] + k [4][64][40]; overlaid by p [4][64][72]
//      [58368,76800)  vt [4][32][72]  (V transposed per head)

__launch_bounds__(512, 4)
__global__ void swin_attn(const float* __restrict__ x,
                          const float* __restrict__ qkv_bias,
                          const float* __restrict__ proj_bias,
                          const __hip_bfloat16* __restrict__ wqkvT,
                          const __hip_bfloat16* __restrict__ wprojT,
                          const __hip_bfloat16* __restrict__ tbl,
                          float* __restrict__ out) {
  __shared__ __align__(16) char smem[76800];
  __hip_bfloat16* a_lds  = (__hip_bfloat16*)smem;             // [64][136]
  __hip_bfloat16* qk_lds = (__hip_bfloat16*)(smem + 17408);   // q then k
  __hip_bfloat16* p_lds  = qk_lds;                            // [4][64][72]
  __hip_bfloat16* vt_lds = (__hip_bfloat16*)(smem + 58368);   // [4][32][72]

  const int tid = threadIdx.x;
  const int lane = tid & 63;
  const int wv = tid >> 6;          // wave 0..7
  const int g = lane >> 4;          // quarter-wave group
  const int c = lane & 15;

  const int widx = blockIdx.x;
  const int b  = widx >> 6;
  const int wy = (widx >> 3) & 7;
  const int wx = widx & 7;
  const int win64 = widx & 63;

  // ---- phase 1: stage shifted x-window as bf16 (rows 49..63 zero) ----
  for (int it = tid; it < 1024; it += 512) {
    int s = it >> 4;
    int l16 = it & 15;
    union { s16x8 v; __hip_bfloat16 h[8]; } u;
    if (s < WSQ) {
      int i = s / 7, j = s - i * 7;
      int hh = wy * 7 + i + SHIFT_SZ; if (hh >= HW) hh -= HW;
      int ww = wx * 7 + j + SHIFT_SZ; if (ww >= HW) ww -= HW;
      const float4* src = (const float4*)(x + (((b * HW + hh) * HW + ww) * CH + l16 * 8));
      float4 f0 = src[0], f1 = src[1];
      u.h[0] = __float2bfloat16(f0.x); u.h[1] = __float2bfloat16(f0.y);
      u.h[2] = __float2bfloat16(f0.z); u.h[3] = __float2bfloat16(f0.w);
      u.h[4] = __float2bfloat16(f1.x); u.h[5] = __float2bfloat16(f1.y);
      u.h[6] = __float2bfloat16(f1.z); u.h[7] = __float2bfloat16(f1.w);
    } else {
      #pragma unroll
      for (int q = 0; q < 8; ++q) u.h[q] = __float2bfloat16(0.f);
    }
    *(s16x8*)(a_lds + s * 136 + l16 * 8) = u.v;
  }
  __syncthreads();

  // ---- phase 2: QKV GEMM (M=64, N=384, K=128); wave wv owns n-tiles 3wv..3wv+2
  {
    f32x4 acc[4][3];
    #pragma unroll
    for (int mt = 0; mt < 4; ++mt)
      #pragma unroll
      for (int ntl = 0; ntl < 3; ++ntl) acc[mt][ntl] = (f32x4){0.f, 0.f, 0.f, 0.f};

    #pragma unroll
    for (int kt = 0; kt < 4; ++kt) {
      s16x8 af[4];
      #pragma unroll
      for (int mt = 0; mt < 4; ++mt)
        af[mt] = *(const s16x8*)(a_lds + (16 * mt + c) * 136 + kt * 32 + g * 8);
      #pragma unroll
      for (int ntl = 0; ntl < 3; ++ntl) {
        int nt = 3 * wv + ntl;
        s16x8 bf = *(const s16x8*)(wqkvT + (16 * nt + c) * 128 + kt * 32 + g * 8);
        #pragma unroll
        for (int mt = 0; mt < 4; ++mt)
          acc[mt][ntl] = __builtin_amdgcn_mfma_f32_16x16x32_bf16(af[mt], bf, acc[mt][ntl], 0, 0, 0);
      }
    }
    // scatter QKV into LDS (Q scaled; V transposed)
    #pragma unroll
    for (int ntl = 0; ntl < 3; ++ntl) {
      int nt = 3 * wv + ntl;
      int n = 16 * nt + c;
      float bias = qkv_bias[n];
      int sel = n >> 7;
      int rem = n & 127;
      int head = rem >> 5;
      int d = rem & 31;
      #pragma unroll
      for (int mt = 0; mt < 4; ++mt)
        #pragma unroll
        for (int r = 0; r < 4; ++r) {
          int s = 16 * mt + 4 * g + r;
          float v = acc[mt][ntl][r] + bias;
          if (sel == 0)
            qk_lds[(head * 64 + s) * 40 + d] = __float2bfloat16(v * 0.17677669529663687f);
          else if (sel == 1)
            qk_lds[10240 + (head * 64 + s) * 40 + d] = __float2bfloat16(v);
          else
            vt_lds[(head * 32 + d) * 72 + s] = __float2bfloat16(v);
        }
    }
  }
  __syncthreads();

  // ---- phase 3: attention; wave = (head h, row-half mh) ----
  const int h = wv >> 1;
  const int mh = wv & 1;
  float den[2][4];
  f32x4 oacc[2][2];
  {
    s16x8 qf[2], kf[4];
    #pragma unroll
    for (int m = 0; m < 2; ++m)
      qf[m] = *(const s16x8*)(qk_lds + (h * 64 + 16 * (2 * mh + m) + c) * 40 + g * 8);
    #pragma unroll
    for (int nt = 0; nt < 4; ++nt)
      kf[nt] = *(const s16x8*)(qk_lds + 10240 + (h * 64 + 16 * nt + c) * 40 + g * 8);
    __syncthreads();   // all q/k reads done -> safe to overlay with P

    f32x4 sacc[2][4];
    #pragma unroll
    for (int m = 0; m < 2; ++m)
      #pragma unroll
      for (int nt = 0; nt < 4; ++nt) {
        sacc[m][nt] = (f32x4){0.f, 0.f, 0.f, 0.f};
        sacc[m][nt] = __builtin_amdgcn_mfma_f32_16x16x32_bf16(qf[m], kf[nt], sacc[m][nt], 0, 0, 0);
      }

    // add bias+mask table, softmax along t (rows live on 16-lane groups)
    const __hip_bfloat16* tb = tbl + (((win64 << 2) + h) << 12);
    #pragma unroll
    for (int m = 0; m < 2; ++m)
      #pragma unroll
      for (int nt = 0; nt < 4; ++nt)
        #pragma unroll
        for (int r = 0; r < 4; ++r) {
          int s = 16 * (2 * mh + m) + 4 * g + r;
          int t = 16 * nt + c;
          sacc[m][nt][r] += __bfloat162float(tb[(s << 6) + t]);
        }
    #pragma unroll
    for (int m = 0; m < 2; ++m)
      #pragma unroll
      for (int r = 0; r < 4; ++r) {
        float mx = fmaxf(fmaxf(sacc[m][0][r], sacc[m][1][r]), fmaxf(sacc[m][2][r], sacc[m][3][r]));
        #pragma unroll
        for (int off = 1; off < 16; off <<= 1) mx = fmaxf(mx, __shfl_xor(mx, off));
        float sum = 0.f;
        #pragma unroll
        for (int nt = 0; nt < 4; ++nt) {
          float e = __expf(sacc[m][nt][r] - mx);
          sacc[m][nt][r] = e;
          sum += e;
        }
        #pragma unroll
        for (int off = 1; off < 16; off <<= 1) sum += __shfl_xor(sum, off);
        den[m][r] = sum;
      }
    // write unnormalized P (bf16) to LDS for transpose into A-fragments
    #pragma unroll
    for (int m = 0; m < 2; ++m)
      #pragma unroll
      for (int nt = 0; nt < 4; ++nt)
        #pragma unroll
        for (int r = 0; r < 4; ++r) {
          int s = 16 * (2 * mh + m) + 4 * g + r;
          int t = 16 * nt + c;
          p_lds[(h * 64 + s) * 72 + t] = __float2bfloat16(sacc[m][nt][r]);
        }
  }
  __syncthreads();

  // ---- PV: O = P @ V  (M=32 rows this wave, N=32, K=64) ----
  #pragma unroll
  for (int m = 0; m < 2; ++m)
    #pragma unroll
    for (int ntd = 0; ntd < 2; ++ntd) oacc[m][ntd] = (f32x4){0.f, 0.f, 0.f, 0.f};
  #pragma unroll
  for (int kt = 0; kt < 2; ++kt) {
    s16x8 pf[2];
    #pragma unroll
    for (int m = 0; m < 2; ++m)
      pf[m] = *(const s16x8*)(p_lds + (h * 64 + 16 * (2 * mh + m) + c) * 72 + kt * 32 + g * 8);
    #pragma unroll
    for (int ntd = 0; ntd < 2; ++ntd) {
      s16x8 vf = *(const s16x8*)(vt_lds + (h * 32 + 16 * ntd + c) * 72 + kt * 32 + g * 8);
      #pragma unroll
      for (int m = 0; m < 2; ++m)
        oacc[m][ntd] = __builtin_amdgcn_mfma_f32_16x16x32_bf16(pf[m], vf, oacc[m][ntd], 0, 0, 0);
    }
  }
  // normalize + concat heads into o buffer (reuses a_lds region)
  #pragma unroll
  for (int m = 0; m < 2; ++m)
    #pragma unroll
    for (int ntd = 0; ntd < 2; ++ntd)
      #pragma unroll
      for (int r = 0; r < 4; ++r) {
        int s = 16 * (2 * mh + m) + 4 * g + r;
        int col = h * 32 + 16 * ntd + c;
        a_lds[s * 136 + col] = __float2bfloat16(oacc[m][ntd][r] / den[m][r]);
      }
  __syncthreads();

  // ---- phase 4: proj GEMM (M=64, N=128, K=128); wave owns n-tile wv ----
  {
    f32x4 pacc[4];
    #pragma unroll
    for (int mt = 0; mt < 4; ++mt) pacc[mt] = (f32x4){0.f, 0.f, 0.f, 0.f};
    #pragma unroll
    for (int kt = 0; kt < 4; ++kt) {
      s16x8 bfp = *(const s16x8*)(wprojT + (16 * wv + c) * 128 + kt * 32 + g * 8);
      #pragma unroll
      for (int mt = 0; mt < 4; ++mt) {
        s16x8 afo = *(const s16x8*)(a_lds + (16 * mt + c) * 136 + kt * 32 + g * 8);
        pacc[mt] = __builtin_amdgcn_mfma_f32_16x16x32_bf16(afo, bfp, pacc[mt], 0, 0, 0);
      }
    }
    float pb = proj_bias[16 * wv + c];
    #pragma unroll
    for (int mt = 0; mt < 4; ++mt)
      #pragma unroll
      for (int r = 0; r < 4; ++r) {
        int s = 16 * mt + 4 * g + r;
        if (s < WSQ) {
          int i = s / 7, j = s - i * 7;
          int hh = wy * 7 + i + SHIFT_SZ; if (hh >= HW) hh -= HW;
          int ww = wx * 7 + j + SHIFT_SZ; if (ww >= HW) ww -= HW;
          out[((b * HW + hh) * HW + ww) * CH + 16 * wv + c] = pacc[mt][r] + pb;
        }
      }
  }
}

extern "C" void kernel_launch(void* const* d_in, const int* in_sizes, int n_in,
                              void* d_out, int out_size, void* d_ws, size_t ws_size,
                              hipStream_t stream) {
  const float* x            = (const float*)d_in[0];
  const float* qkv_kernel   = (const float*)d_in[1];
  const float* qkv_bias     = (const float*)d_in[2];
  const float* proj_kernel  = (const float*)d_in[3];
  const float* proj_bias    = (const float*)d_in[4];
  const float* rel_pos_tbl  = (const float*)d_in[5];
  float* out = (float*)d_out;

  __hip_bfloat16* wsb    = (__hip_bfloat16*)d_ws;
  __hip_bfloat16* wqkvT  = wsb;            // 49152 elems
  __hip_bfloat16* wprojT = wsb + 49152;    // 16384 elems
  __hip_bfloat16* tbl    = wsb + 65536;    // 1048576 elems

  prep_weights<<<dim3(192), dim3(256), 0, stream>>>(qkv_kernel, proj_kernel, wsb);
  prep_tbl<<<dim3(4096), dim3(256), 0, stream>>>(rel_pos_tbl, tbl);
  swin_attn<<<dim3(4096), dim3(512), 0, stream>>>(x, qkv_bias, proj_bias,
                                                  wqkvT, wprojT, tbl, out);
}